// Round 1
// 140629.358 us; speedup vs baseline: 1.2955x; 1.2955x over previous
//
#include <hip/hip_runtime.h>
#include <hip/hip_fp16.h>
#include <cstddef>

typedef unsigned int uint32;

#define B_   32
#define TE_  512
#define TD_  512
#define NM_  80
#define PRE_ 256
#define EH_  512
#define AH_  1024
#define AD_  128

__device__ __forceinline__ float sigf(float x) { return 1.0f / (1.0f + expf(-x)); }

// ---------------- agent-scope (cross-XCD coherent) access helpers ----------------
// All cross-block communicated data goes through these: stores are write-through
// past L2 (visible at L3), loads bypass L2 (read from L3). This keeps the per-XCD
// L2s VALID across phases (no buffer_inv / wbl2 ever executes in this kernel),
// so read-only data (penc/enct/qw/pn/lc) stays L2-resident for all 512 steps.
__device__ __forceinline__ float agl(const float* p) {
  return __hip_atomic_load(p, __ATOMIC_RELAXED, __HIP_MEMORY_SCOPE_AGENT);
}
__device__ __forceinline__ void ags(float* p, float v) {
  __hip_atomic_store(p, v, __ATOMIC_RELAXED, __HIP_MEMORY_SCOPE_AGENT);
}
__device__ __forceinline__ float4 agl4(const float* p) {
  float4 r; r.x = agl(p); r.y = agl(p + 1); r.z = agl(p + 2); r.w = agl(p + 3);
  return r;
}

// Hand-rolled grid barrier: 2-level monotonic counter tree, relaxed agent atomics
// only — NO acquire/release fence, so no L2 invalidate / writeback. Data ordering:
// every thread's ags() stores are drained by the compiler-emitted
// s_waitcnt vmcnt(0) before the s_barrier of __syncthreads(); the arrive happens
// after that, so any block that observes the root counter sees all prior data.
__device__ __forceinline__ void gsync(uint32* bar, unsigned bep) {
  __syncthreads();
  if (threadIdx.x == 0) {
    asm volatile("s_waitcnt vmcnt(0)" ::: "memory");
    uint32* leaf = bar + (blockIdx.x >> 5) * 32;   // 8 leaves x 32 blocks, line-spaced
    uint32* root = bar + 256;
    uint32 prev = __hip_atomic_fetch_add(leaf, 1u, __ATOMIC_RELAXED, __HIP_MEMORY_SCOPE_AGENT);
    if (prev + 1u == 32u * bep)
      __hip_atomic_fetch_add(root, 1u, __ATOMIC_RELAXED, __HIP_MEMORY_SCOPE_AGENT);
    int spins = 0;
    while (__hip_atomic_load(root, __ATOMIC_RELAXED, __HIP_MEMORY_SCOPE_AGENT) < 8u * bep) {
      __builtin_amdgcn_s_sleep(2);
      if (++spins > 20000000) break;   // safety valve: fail instead of hang
    }
  }
  __syncthreads();
}

// sum over each 16-lane row via DPP (VALU pipe, no LDS)
__device__ __forceinline__ float rowsum16(float v) {
  int vi;
  vi = __float_as_int(v);
  v += __int_as_float(__builtin_amdgcn_update_dpp(0, vi, 0xB1, 0xF, 0xF, true));  // quad xor1
  vi = __float_as_int(v);
  v += __int_as_float(__builtin_amdgcn_update_dpp(0, vi, 0x4E, 0xF, 0xF, true));  // quad xor2
  vi = __float_as_int(v);
  v += __int_as_float(__builtin_amdgcn_update_dpp(0, vi, 0x124, 0xF, 0xF, true)); // row_ror:4
  vi = __float_as_int(v);
  v += __int_as_float(__builtin_amdgcn_update_dpp(0, vi, 0x128, 0xF, 0xF, true)); // row_ror:8
  return v;
}

// ---------------- prologue: LSTM weight packing (fp16, LDS-resident layouts) ----
__global__ __launch_bounds__(256) void k_pack_lstm2(
    const float* __restrict__ awih, const float* __restrict__ awhh,
    const float* __restrict__ dwih, const float* __restrict__ dwhh,
    uint32* __restrict__ wal, uint32* __restrict__ wdl, uint32* __restrict__ wdt)
{
  long gid = blockIdx.x * 256L + threadIdx.x;
  const long N1 = 3686400L, N2 = 4603904L, N3 = 655360L;
  if (gid < N1) {
    int blk = (int)(gid / 28800), rem = (int)(gid % 28800);
    int r2 = rem % 900;
    int ks = rem / 900;
    uint32 out = 0;
    if (r2 < 896) {
      int kq = r2 >> 4, rd = r2 & 15;
      int k = kq * 32 + ks;
      int rp0 = blk * 32 + 2 * rd, rp1 = rp0 + 1;
      int row0 = (rp0 & 3) * 1024 + (rp0 >> 2);
      int row1 = (rp1 & 3) * 1024 + (rp1 >> 2);
      float w0 = (k < 768) ? awih[(size_t)row0 * 768 + k] : awhh[(size_t)row0 * 1024 + k - 768];
      float w1 = (k < 768) ? awih[(size_t)row1 * 768 + k] : awhh[(size_t)row1 * 1024 + k - 768];
      __half2 h = __floats2half2_rn(w0, w1);
      out = *(uint32*)&h;
    }
    wal[gid] = out;
  } else if (gid < N1 + N2) {
    long g = gid - N1;
    int blk = (int)(g / 35968), rem = (int)(g % 35968);
    int r2 = rem % 1124;
    int ks = rem / 1124;
    uint32 out = 0;
    if (r2 < 1120) {
      int kq = r2 >> 4, rd = r2 & 15;
      int k = kq * 32 + ks;
      int rp0 = blk * 32 + 2 * rd, rp1 = rp0 + 1;
      int row0 = (rp0 & 3) * 1024 + (rp0 >> 2);
      int row1 = (rp1 & 3) * 1024 + (rp1 >> 2);
      float w0 = (k < 1536) ? dwih[(size_t)row0 * 1536 + k] : dwhh[(size_t)row0 * 1024 + k - 1536];
      float w1 = (k < 1536) ? dwih[(size_t)row1 * 1536 + k] : dwhh[(size_t)row1 * 1024 + k - 1536];
      __half2 h = __floats2half2_rn(w0, w1);
      out = *(uint32*)&h;
    }
    wdl[g] = out;
  } else if (gid < N1 + N2 + N3) {
    long g = gid - N1 - N2;
    int blk = (int)(g / 5120), rem = (int)(g % 5120);
    int rd2 = rem & 3, rg = (rem >> 2) & 3, ks = (rem >> 4) & 31, i = rem >> 9;
    int k = 2240 + 32 * i + ks;
    int r0 = rg * 8 + 2 * rd2;
    int rp0 = blk * 32 + r0, rp1 = rp0 + 1;
    int row0 = (rp0 & 3) * 1024 + (rp0 >> 2);
    int row1 = (rp1 & 3) * 1024 + (rp1 >> 2);
    float w0 = (k < 1536) ? dwih[(size_t)row0 * 1536 + k] : dwhh[(size_t)row0 * 1024 + k - 1536];
    float w1 = (k < 1536) ? dwih[(size_t)row1 * 1536 + k] : dwhh[(size_t)row1 * 1024 + k - 1536];
    __half2 h = __floats2half2_rn(w0, w1);
    wdt[g] = *(uint32*)&h;
  }
}

__global__ __launch_bounds__(256) void k_pack_small(
    const float* __restrict__ w1, const float* __restrict__ w2,
    const float* __restrict__ mw, const float* __restrict__ pw,
    const float* __restrict__ abih, const float* __restrict__ abhh,
    const float* __restrict__ dbih, const float* __restrict__ dbhh,
    const float* __restrict__ lw, const float* __restrict__ cw,
    float* __restrict__ w1t, float* __restrict__ w2t, float* __restrict__ mt,
    float* __restrict__ pjt, float* __restrict__ ba, float* __restrict__ bd,
    float* __restrict__ lc)
{
  int gid = blockIdx.x * 256 + threadIdx.x;
  if (gid < 20480) { int k = gid / 256, j = gid % 256; w1t[gid] = w1[j * 80 + k]; return; }
  gid -= 20480;
  if (gid < 65536) { int k = gid / 256, j = gid % 256; w2t[gid] = w2[j * 256 + k]; return; }
  gid -= 65536;
  if (gid < 65536) { int e = gid / 128, d = gid % 128; mt[gid] = mw[d * 512 + e]; return; }
  gid -= 65536;
  if (gid < 122880) { int k = gid / 80, m = gid % 80; pjt[gid] = pw[m * 1536 + k]; return; }
  gid -= 122880;
  if (gid < 4096) { int j = gid >> 2, g = gid & 3, row = g * 1024 + j; ba[gid] = abih[row] + abhh[row]; return; }
  gid -= 4096;
  if (gid < 4096) { int j = gid >> 2, g = gid & 3, row = g * 1024 + j; bd[gid] = dbih[row] + dbhh[row]; return; }
  gid -= 4096;
  if (gid < 7936) {
    int c = gid / (31 * 128), rem = gid % (31 * 128);
    int kk = rem / 128, d = rem % 128;
    float s = 0.f;
    for (int f = 0; f < 32; ++f) s += lw[d * 32 + f] * cw[(f * 2 + c) * 31 + kk];
    lc[gid] = s;
  }
}

// ---------------- prologue: prenet (verified) ----------------
__global__ __launch_bounds__(256) void k_prenet(
    const float* __restrict__ targets, const float* __restrict__ w1t,
    const float* __restrict__ b1, const float* __restrict__ w2t,
    const float* __restrict__ b2, float* __restrict__ pn)
{
  int t = blockIdx.x, tid = threadIdx.x;
  __shared__ float X[32][80];
  __shared__ float h1[256][33];
  for (int i = tid; i < 2560; i += 256) {
    int b = i / 80, m = i % 80;
    X[b][m] = (t == 0) ? 0.f : targets[((size_t)b * TD_ + (t - 1)) * NM_ + m];
  }
  __syncthreads();
  int j = tid;
  float bj = b1[j];
  for (int bt = 0; bt < 4; ++bt) {
    float acc[8];
#pragma unroll
    for (int i = 0; i < 8; ++i) acc[i] = bj;
    for (int k = 0; k < 80; ++k) {
      float w = w1t[k * 256 + j];
#pragma unroll
      for (int i = 0; i < 8; ++i) acc[i] += w * X[bt * 8 + i][k];
    }
#pragma unroll
    for (int i = 0; i < 8; ++i) h1[j][bt * 8 + i] = fmaxf(acc[i], 0.f);
  }
  __syncthreads();
  float cj = b2[j];
  float* out = pn + (size_t)t * PRE_ * B_;
  for (int bt = 0; bt < 4; ++bt) {
    float acc[8];
#pragma unroll
    for (int i = 0; i < 8; ++i) acc[i] = cj;
    for (int k = 0; k < 256; ++k) {
      float w = w2t[k * 256 + j];
#pragma unroll
      for (int i = 0; i < 8; ++i) acc[i] += w * h1[k][bt * 8 + i];
    }
#pragma unroll
    for (int i = 0; i < 8; ++i) out[j * 32 + bt * 8 + i] = fmaxf(acc[i], 0.f);
  }
}

// ---------------- prologue: processed_enc (verified) ----------------
__global__ __launch_bounds__(256) void k_penc(
    const float* __restrict__ enc, const float* __restrict__ mt,
    float* __restrict__ penc)
{
  int t = blockIdx.x, tid = threadIdx.x;
  __shared__ float encL[32][256];
  __shared__ float red[128][8][2];
  int d = tid & 127, s = tid >> 7;
  float acc[4][8];
#pragma unroll
  for (int bt = 0; bt < 4; ++bt)
#pragma unroll
    for (int i = 0; i < 8; ++i) acc[bt][i] = 0.f;
  for (int eh = 0; eh < 2; ++eh) {
    for (int i = tid; i < 8192; i += 256) {
      int b = i >> 8, e = i & 255;
      encL[b][e] = enc[((size_t)b * TE_ + t) * EH_ + eh * 256 + e];
    }
    __syncthreads();
    for (int bt = 0; bt < 4; ++bt) {
      for (int el = s * 128; el < s * 128 + 128; ++el) {
        float w = mt[(eh * 256 + el) * 128 + d];
#pragma unroll
        for (int i = 0; i < 8; ++i) acc[bt][i] += w * encL[bt * 8 + i][el];
      }
    }
    __syncthreads();
  }
  for (int bt = 0; bt < 4; ++bt) {
#pragma unroll
    for (int i = 0; i < 8; ++i) red[d][i][s] = acc[bt][i];
    __syncthreads();
    if (s == 0) {
#pragma unroll
      for (int i = 0; i < 8; ++i)
        penc[((size_t)t * AD_ + d) * 32 + bt * 8 + i] = red[d][i][0] + red[d][i][1];
    }
    __syncthreads();
  }
}

// ---------------- prologue: enc transpose to fp16 [b][e][t] ----------------
__global__ __launch_bounds__(256) void k_enct(
    const float* __restrict__ enc, __half* __restrict__ enct)
{
  int blk = blockIdx.x, tid = threadIdx.x;
  int b = blk >> 6, t0 = ((blk >> 3) & 7) * 64, e0 = (blk & 7) * 64;
  __shared__ float tile[64][65];
  for (int i = 0; i < 16; ++i) {
    int tl = i * 4 + (tid >> 6), e = tid & 63;
    tile[tl][e] = enc[((size_t)b * TE_ + t0 + tl) * EH_ + e0 + e];
  }
  __syncthreads();
  for (int i = 0; i < 16; ++i) {
    int el = i * 4 + (tid >> 6), tl = tid & 63;
    enct[((size_t)b * EH_ + e0 + el) * TE_ + t0 + tl] = __float2half(tile[tl][el]);
  }
}

// ---------------- persistent step kernel ----------------
struct KP {
  const uint32* wal; const uint32* wdl; const uint4* wdt;
  const float* pn; const float* penc; const __half* enct;
  const float* qw; const float* ww; const float* pjt; const float* pjb;
  const float* lc; const float* ba; const float* bd;
  float* ah; float* ac; float* dh; float* dc; float* ctx2; float* aw; float* aws;
  float* enp; float* mel; float* align;
  uint32* bar;
};

template<int T1, int T2>
__device__ __forceinline__ void stage_xc(int c, int nch,
    const float* __restrict__ xp0, const float* __restrict__ xp1,
    const float* __restrict__ xp2, float* __restrict__ XC,
    float4& st, int kidx, int b4)
{
  __syncthreads();
  *(float4*)&XC[kidx * 36 + b4] = st;
  __syncthreads();
  if (c + 1 < nch) {
    int kg = (c + 1) * 64 + kidx;
    const float* src = (kg < T1) ? xp0 + (size_t)kg * 32
                     : (kg < T2) ? xp1 + (size_t)(kg - T1) * 32
                                 : xp2 + (size_t)(kg - T2) * 32;
    st = agl4(src + b4);
  }
}

__device__ __forceinline__ void fma2(uint4 wv, const float* __restrict__ XC,
                                     int xb, float* acc)
{
  const __half2* hp = (const __half2*)&wv;
  float w[8];
#pragma unroll
  for (int d = 0; d < 4; ++d) {
    float2 f = __half22float2(hp[d]);
    w[2 * d] = f.x; w[2 * d + 1] = f.y;
  }
  float4 xa = *(const float4*)&XC[xb];
  float4 xc2 = *(const float4*)&XC[xb + 4];
  float x[8] = {xa.x, xa.y, xa.z, xa.w, xc2.x, xc2.y, xc2.z, xc2.w};
#pragma unroll
  for (int ri = 0; ri < 8; ++ri)
#pragma unroll
    for (int bi = 0; bi < 8; ++bi)
      acc[ri * 8 + bi] = fmaf(w[ri], x[bi], acc[ri * 8 + bi]);
}

__device__ __forceinline__ void lstm_finish(
    float* acc, float* __restrict__ GT, const float* __restrict__ bias,
    float* __restrict__ cst, float* __restrict__ hout,
    int rp0, int tid, int ks, int bq, int rg)
{
#pragma unroll
  for (int i = 0; i < 64; ++i) {
    float v = rowsum16(acc[i]);
    acc[i] = v + __shfl_xor(v, 16);
  }
  if (ks == 0) {
#pragma unroll
    for (int ri = 0; ri < 8; ++ri) {
      *(float4*)&GT[(rg * 8 + ri) * 32 + bq * 8] =
          make_float4(acc[ri * 8 + 0], acc[ri * 8 + 1], acc[ri * 8 + 2], acc[ri * 8 + 3]);
      *(float4*)&GT[(rg * 8 + ri) * 32 + bq * 8 + 4] =
          make_float4(acc[ri * 8 + 4], acc[ri * 8 + 5], acc[ri * 8 + 6], acc[ri * 8 + 7]);
    }
  }
  __syncthreads();
  if (tid < 256) {
    int jl = tid >> 5, b = tid & 31;
    float gi = GT[(jl * 4 + 0) * 32 + b] + bias[rp0 + jl * 4 + 0];
    float gf = GT[(jl * 4 + 1) * 32 + b] + bias[rp0 + jl * 4 + 1];
    float gg = GT[(jl * 4 + 2) * 32 + b] + bias[rp0 + jl * 4 + 2];
    float go = GT[(jl * 4 + 3) * 32 + b] + bias[rp0 + jl * 4 + 3];
    int j = (rp0 >> 2) + jl;
    float c0 = cst[j * 32 + b];                 // block-private: plain cached r/w
    float c2 = sigf(gf) * c0 + sigf(gi) * tanhf(gg);
    float h2 = sigf(go) * tanhf(c2);
    cst[j * 32 + b] = c2;
    ags(&hout[j * 32 + b], h2);                 // communicated: agent store
  }
}

__device__ __forceinline__ void run_lstm_a(const KP& p, int t, int pp, int pc,
    uint32* WlU, float* XC, float* GT, int tid, int ks, int bq, int rg,
    int kidx, int b4, int blk)
{
  float acc[64];
#pragma unroll
  for (int i = 0; i < 64; ++i) acc[i] = 0.f;
  const float* xp0 = p.pn + (size_t)t * 8192;
  const float* xp1 = p.ctx2 + pp * 16384;
  const float* xp2 = p.ah + pp * 32768;
  float4 st;
  {
    int kg = kidx;
    const float* src = (kg < 256) ? xp0 + (size_t)kg * 32
                     : (kg < 768) ? xp1 + (size_t)(kg - 256) * 32
                                  : xp2 + (size_t)(kg - 768) * 32;
    st = agl4(src + b4);
  }
  const int wb = ks * 900 + rg * 4;
  const int xr = ks * 36 + bq * 8;
  for (int c = 0; c < 28; ++c) {
    stage_xc<256, 768>(c, 28, xp0, xp1, xp2, XC, st, kidx, b4);
    fma2(*(const uint4*)&WlU[wb + (2 * c) * 16], XC, xr, acc);
    fma2(*(const uint4*)&WlU[wb + (2 * c + 1) * 16], XC, xr + 32 * 36, acc);
  }
  lstm_finish(acc, GT, p.ba, p.ac, p.ah + pc * 32768, blk * 32, tid, ks, bq, rg);
}

__device__ __forceinline__ void run_lstm_d(const KP& p,
    const float* xp0, const float* xp1, const float* xp2, float* dh_w,
    uint32* WlU, float* XC, float* GT, const uint4* wt,
    int tid, int ks, int bq, int rg, int kidx, int b4, int blk)
{
  float acc[64];
#pragma unroll
  for (int i = 0; i < 64; ++i) acc[i] = 0.f;
  float4 st;
  st = agl4(xp0 + (size_t)kidx * 32 + b4);  // chunk 0 all in xp0 (1024 wide)
  const int wb = ks * 1124 + rg * 4;
  const int xr = ks * 36 + bq * 8;
  for (int c = 0; c < 35; ++c) {
    stage_xc<1024, 1536>(c, 40, xp0, xp1, xp2, XC, st, kidx, b4);
    fma2(*(const uint4*)&WlU[wb + (2 * c) * 16], XC, xr, acc);
    fma2(*(const uint4*)&WlU[wb + (2 * c + 1) * 16], XC, xr + 32 * 36, acc);
  }
#pragma unroll
  for (int c2 = 0; c2 < 5; ++c2) {
    stage_xc<1024, 1536>(35 + c2, 40, xp0, xp1, xp2, XC, st, kidx, b4);
    fma2(wt[c2 * 2], XC, xr, acc);
    fma2(wt[c2 * 2 + 1], XC, xr + 32 * 36, acc);
  }
  lstm_finish(acc, GT, p.bd, p.dc, dh_w, (blk - 128) * 32, tid, ks, bq, rg);
}

__device__ __forceinline__ void mel_block(
    const float* __restrict__ dhp, const float* __restrict__ ctp,
    const float* __restrict__ pjt, const float* __restrict__ pjb,
    float* __restrict__ mel, int bb, int tt, float* S, int tid)
{
  float* xo = S + 1536;
  float* ro = S + 3072;
  for (int i = tid; i < 1536; i += 512)
    xo[i] = (i < 1024) ? agl(&dhp[i * 32 + bb]) : agl(&ctp[(i - 1024) * 32 + bb]);
  __syncthreads();
  if (tid < 480) {
    int m = tid % 80, k2 = tid / 80;
    float a2 = 0.f;
    for (int k = k2 * 256; k < k2 * 256 + 256; ++k) a2 += pjt[k * 80 + m] * xo[k];
    ro[m * 8 + k2] = a2;
  }
  __syncthreads();
  if (tid < 80) {
    float s3 = pjb[tid];
#pragma unroll
    for (int k = 0; k < 6; ++k) s3 += ro[tid * 8 + k];
    mel[((size_t)bb * TD_ + tt) * NM_ + tid] = s3;
  }
}

__global__ __launch_bounds__(512) void k_step(KP p)
{
  extern __shared__ float LDSF[];
  const int blk = blockIdx.x, tid = threadIdx.x;
  const int ks = tid & 31, bq = (tid >> 5) & 3, rg = tid >> 7;
  const int kidx = tid >> 3, b4 = (tid & 7) * 4;
  const bool isA = blk < 128;
  float* SC = LDSF + (isA ? 28800 : 35968);
  float* XC = SC;
  float* GT = SC + 2304;
  uint32* WlU = (uint32*)LDSF;
  unsigned bep = 0;

  // one-time: weights into LDS (+VGPR tail for D)
  {
    const uint32* src = isA ? p.wal + (size_t)blk * 28800
                            : p.wdl + (size_t)(blk - 128) * 35968;
    int n4 = isA ? 7200 : 8992;
    for (int i = tid; i < n4; i += 512)
      ((uint4*)WlU)[i] = ((const uint4*)src)[i];
  }
  uint4 wt[10];
  if (!isA) {
#pragma unroll
    for (int i = 0; i < 10; ++i)
      wt[i] = p.wdt[(size_t)(blk - 128) * 1280 + (i * 32 + ks) * 4 + rg];
  }
  __syncthreads();

  for (int t = 0; t < TD_; ++t) {
    const int pc = t & 1, pp = pc ^ 1;
    // ---- PA: lstm_a(t) [0..127] || lstm_d(t-1) [128..255] ----
    if (isA) {
      run_lstm_a(p, t, pp, pc, WlU, XC, GT, tid, ks, bq, rg, kidx, b4, blk);
    } else if (t > 0) {
      run_lstm_d(p, p.ah + pp * 32768, p.ctx2 + pp * 16384, p.dh + pc * 32768,
                 p.dh + pp * 32768, WlU, XC, GT, wt, tid, ks, bq, rg, kidx, b4, blk);
    }
    bep += 1; gsync(p.bar, bep);
    // ---- PB: q (from ah[pc], LDS-chunked) + location conv + energies partials ----
    {
      int tc = blk >> 3, ds = blk & 7;
      int t0 = tc * 16, d0 = ds * 16;
      float* qs  = SC;            // 512
      float* wws = SC + 512;      // 16
      float* AHC = SC + 528;      // 2048 (chunk buffer, later reused by win/lcs)
      float* win = SC + 528;      // 2944
      float* lcs = SC + 528 + 2944; // 992
      if (tid < 16) wws[tid] = p.ww[d0 + tid];
      int bb2 = tid & 31, dl = tid >> 5;
      {
        const float* ahsrc = p.ah + pc * 32768;
        const float* qbase = p.qw + (size_t)(d0 + dl) * 1024;
        float qacc = 0.f;
        float pf0, pf1, pf2, pf3;
        {
          const float* s0 = ahsrc + tid * 4;
          pf0 = agl(s0); pf1 = agl(s0 + 1); pf2 = agl(s0 + 2); pf3 = agl(s0 + 3);
        }
        for (int ch = 0; ch < 16; ++ch) {
          __syncthreads();
          float* dst = AHC + tid * 4;
          dst[0] = pf0; dst[1] = pf1; dst[2] = pf2; dst[3] = pf3;
          __syncthreads();
          if (ch < 15) {
            const float* s0 = ahsrc + (ch + 1) * 2048 + tid * 4;
            pf0 = agl(s0); pf1 = agl(s0 + 1); pf2 = agl(s0 + 2); pf3 = agl(s0 + 3);
          }
          const float* qrow = qbase + ch * 64;
#pragma unroll
          for (int jj = 0; jj < 64; jj += 4) {
            float4 qv = *(const float4*)(qrow + jj);
            qacc = fmaf(qv.x, AHC[(jj + 0) * 32 + bb2], qacc);
            qacc = fmaf(qv.y, AHC[(jj + 1) * 32 + bb2], qacc);
            qacc = fmaf(qv.z, AHC[(jj + 2) * 32 + bb2], qacc);
            qacc = fmaf(qv.w, AHC[(jj + 3) * 32 + bb2], qacc);
          }
        }
        __syncthreads();
        qs[dl * 32 + bb2] = qacc;
      }
      for (int i = tid; i < 2944; i += 512) {
        int c = i / 1472, r = (i >> 5) % 46, bb = i & 31;
        int tg = t0 - 15 + r;
        float v = 0.f;
        if (tg >= 0 && tg < 512) v = agl((c ? p.aws : p.aw) + tg * 32 + bb);
        win[i] = v;
      }
      for (int i = tid; i < 992; i += 512) {
        int c = i / 496, kk = (i >> 4) % 31, dl2 = i & 15;
        lcs[i] = p.lc[(c * 31 + kk) * 128 + d0 + dl2];
      }
      __syncthreads();
      {
        int bb = tid & 31, th = tid >> 5;
        int tt = t0 + th;
        float pa[16];
#pragma unroll
        for (int i = 0; i < 16; ++i) pa[i] = 0.f;
        for (int c = 0; c < 2; ++c) {
          for (int kk = 0; kk < 31; ++kk) {
            float wv = win[c * 1472 + (th + kk) * 32 + bb];
            const float4* lr = (const float4*)(lcs + c * 496 + kk * 16);
            float4 l0 = lr[0], l1 = lr[1], l2 = lr[2], l3 = lr[3];
            pa[0]  += l0.x * wv; pa[1]  += l0.y * wv; pa[2]  += l0.z * wv; pa[3]  += l0.w * wv;
            pa[4]  += l1.x * wv; pa[5]  += l1.y * wv; pa[6]  += l1.z * wv; pa[7]  += l1.w * wv;
            pa[8]  += l2.x * wv; pa[9]  += l2.y * wv; pa[10] += l2.z * wv; pa[11] += l2.w * wv;
            pa[12] += l3.x * wv; pa[13] += l3.y * wv; pa[14] += l3.z * wv; pa[15] += l3.w * wv;
          }
        }
        float epv = 0.f;
#pragma unroll
        for (int dl2 = 0; dl2 < 16; ++dl2) {
          float v = qs[dl2 * 32 + bb] + p.penc[((size_t)tt * 128 + d0 + dl2) * 32 + bb] + pa[dl2];
          epv += wws[dl2] * tanhf(v);
        }
        ags(&p.enp[(size_t)bb * 4096 + tt * 8 + ds], epv);
      }
    }
    bep += 1; gsync(p.bar, bep);
    // ---- PC: softmax + ctx (+aw/aws/align, +mel(t-1)) ----
    {
      int bb = blk >> 3, et = blk & 7;
      float* Sr  = SC;
      float* awL = SC + 512;
      float* cr  = SC + 1024;
      const float* epb = p.enp + (size_t)bb * 4096 + tid * 8;
      float e = agl(epb) + agl(epb + 1) + agl(epb + 2) + agl(epb + 3)
              + agl(epb + 4) + agl(epb + 5) + agl(epb + 6) + agl(epb + 7);
      Sr[tid] = e; __syncthreads();
      for (int off = 256; off; off >>= 1) {
        if (tid < off) Sr[tid] = fmaxf(Sr[tid], Sr[tid + off]);
        __syncthreads();
      }
      float mx = Sr[0]; __syncthreads();
      float x = expf(e - mx);
      Sr[tid] = x; __syncthreads();
      for (int off = 256; off; off >>= 1) {
        if (tid < off) Sr[tid] += Sr[tid + off];
        __syncthreads();
      }
      float a = x * (1.f / Sr[0]);
      awL[tid] = a;
      __syncthreads();
      int el = tid & 63, ts = tid >> 6;
      const __half2* eb = (const __half2*)(p.enct +
          ((size_t)(bb * 512 + et * 64 + el)) * 512 + ts * 64);
      float acc = 0.f;
#pragma unroll 8
      for (int i = 0; i < 32; ++i) {
        float2 f = __half22float2(eb[i]);
        acc += awL[ts * 64 + 2 * i] * f.x + awL[ts * 64 + 2 * i + 1] * f.y;
      }
      cr[ts * 64 + el] = acc;
      __syncthreads();
      if (tid < 64) {
        float s2 = 0.f;
#pragma unroll
        for (int k = 0; k < 8; ++k) s2 += cr[k * 64 + tid];
        ags(&p.ctx2[pc * 16384 + (et * 64 + tid) * 32 + bb], s2);
      }
      if (et == 0) {
        ags(&p.aw[tid * 32 + bb], a);
        float os = agl(&p.aws[tid * 32 + bb]);
        ags(&p.aws[tid * 32 + bb], os + a);
        p.align[((size_t)bb * TD_ + t) * TE_ + tid] = a;
      }
      if (et == 1 && t > 0) {
        mel_block(p.dh + pp * 32768, p.ctx2 + pp * 16384, p.pjt, p.pjb,
                  p.mel, bb, t - 1, SC, tid);
      }
    }
    bep += 1; gsync(p.bar, bep);
  }
  // ---- epilogue: lstm_d(511) then mel(511). t=512 -> pc=0, pp=1 ----
  if (!isA) {
    run_lstm_d(p, p.ah + 32768, p.ctx2 + 16384, p.dh + 0,
               p.dh + 32768, WlU, XC, GT, wt, tid, ks, bq, rg, kidx, b4, blk);
  }
  bep += 1; gsync(p.bar, bep);
  if (blk < 32) {
    mel_block(p.dh + 32768, p.ctx2 + 16384, p.pjt, p.pjb, p.mel, blk, 511, SC, tid);
  }
}

extern "C" void kernel_launch(void* const* d_in, const int* in_sizes, int n_in,
                              void* d_out, int out_size, void* d_ws, size_t ws_size,
                              hipStream_t stream)
{
  const float* enc     = (const float*)d_in[0];
  const float* targets = (const float*)d_in[1];
  const float* pw1  = (const float*)d_in[2];
  const float* pb1  = (const float*)d_in[3];
  const float* pw2  = (const float*)d_in[4];
  const float* pb2  = (const float*)d_in[5];
  const float* mw   = (const float*)d_in[6];
  const float* qw   = (const float*)d_in[7];
  const float* www  = (const float*)d_in[8];
  const float* lw   = (const float*)d_in[9];
  const float* cw   = (const float*)d_in[10];
  const float* awih = (const float*)d_in[11];
  const float* awhh = (const float*)d_in[12];
  const float* abih = (const float*)d_in[13];
  const float* abhh = (const float*)d_in[14];
  const float* dwih = (const float*)d_in[15];
  const float* dwhh = (const float*)d_in[16];
  const float* dbih = (const float*)d_in[17];
  const float* dbhh = (const float*)d_in[18];
  const float* pjw  = (const float*)d_in[19];
  const float* pjb  = (const float*)d_in[20];

  uint32* wsb = (uint32*)d_ws;
  uint32* WAL2 = wsb;                      // 3,686,400 dw
  uint32* WDL2 = WAL2 + 3686400;           // 4,603,904 dw
  uint32* WDT  = WDL2 + 4603904;           // 655,360 dw (16B aligned)
  __half* ENCT = (__half*)(WDT + 655360);  // 8,388,608 halfs = 4,194,304 dw
  float*  PN   = (float*)(WDT + 655360 + 4194304);  // 4,194,304
  float*  PENC = PN + 4194304;             // 2,097,152
  float*  W1T  = PENC + 2097152;           // 20,480  (ENP aliases W1T..)
  float*  W2T  = W1T + 20480;              // 65,536
  float*  MT   = W2T + 65536;              // 65,536
  float*  PJT  = MT + 65536;               // 122,880
  float*  LC   = PJT + 122880;             // 7,936
  float*  BA   = LC + 7936;                // 4,096
  float*  BD   = BA + 4096;                // 4,096
  float*  STATE = BD + 4096;               // 262,144 + barrier 512
  float*  AHb  = STATE;                    // 65,536 (2 parities)
  float*  ACb  = AHb + 65536;              // 32,768
  float*  DHb  = ACb + 32768;              // 65,536 (2 parities)
  float*  DCb  = DHb + 65536;              // 32,768
  float*  CTXb = DCb + 32768;              // 32,768 (2 parities)
  float*  AWb  = CTXb + 32768;             // 16,384
  float*  AWSb = AWb + 16384;              // 16,384
  uint32* BARC = (uint32*)(STATE + 262144); // 512 dw barrier counters
  float*  ENP  = W1T;                      // alias 131,072 <= 151,552

  hipMemsetAsync(STATE, 0, (size_t)(262144 + 512) * sizeof(float), stream);

  float* mel = (float*)d_out;
  float* align = mel + (size_t)B_ * TD_ * NM_;

  k_pack_lstm2<<<34944, 256, 0, stream>>>(awih, awhh, dwih, dwhh, WAL2, WDL2, WDT);
  k_pack_small<<<1135, 256, 0, stream>>>(pw1, pw2, mw, pjw, abih, abhh, dbih, dbhh,
                                         lw, cw, W1T, W2T, MT, PJT, BA, BD, LC);
  k_prenet<<<512, 256, 0, stream>>>(targets, W1T, pb1, W2T, pb2, PN);
  k_penc<<<512, 256, 0, stream>>>(enc, MT, PENC);
  k_enct<<<2048, 256, 0, stream>>>(enc, ENCT);

  KP kp;
  kp.wal = WAL2; kp.wdl = WDL2; kp.wdt = (const uint4*)WDT;
  kp.pn = PN; kp.penc = PENC; kp.enct = ENCT;
  kp.qw = qw; kp.ww = www; kp.pjt = PJT; kp.pjb = pjb;
  kp.lc = LC; kp.ba = BA; kp.bd = BD;
  kp.ah = AHb; kp.ac = ACb; kp.dh = DHb; kp.dc = DCb;
  kp.ctx2 = CTXb; kp.aw = AWb; kp.aws = AWSb;
  kp.enp = ENP; kp.mel = mel; kp.align = align;
  kp.bar = BARC;

  hipFuncSetAttribute((const void*)k_step,
                      hipFuncAttributeMaxDynamicSharedMemorySize, 161728);
  void* kargs[] = { &kp };
  hipLaunchCooperativeKernel((const void*)k_step, dim3(256), dim3(512), kargs,
                             161728, stream);
}

// Round 2
// 126111.267 us; speedup vs baseline: 1.4447x; 1.1151x over previous
//
#include <hip/hip_runtime.h>
#include <hip/hip_fp16.h>
#include <cstddef>

typedef unsigned int uint32;

#define B_   32
#define TE_  512
#define TD_  512
#define NM_  80
#define PRE_ 256
#define EH_  512
#define AH_  1024
#define AD_  128

__device__ __forceinline__ float sigf(float x) { return 1.0f / (1.0f + expf(-x)); }

// ---------------- agent-scope (cross-XCD coherent) access helpers ----------------
// Used ONLY for low-reuse mutable data (aw/aws windows, enp) and all cross-block
// STORES (write-through so data lands at L3). High-reuse state (ah/dh/ctx) is
// versioned write-once memory read via PLAIN CACHED loads: a stale L2 line is
// impossible because no versioned address is ever read before its unique write,
// and nothing in this kernel invalidates L2 (so penc/enct/qw stay L2-resident).
__device__ __forceinline__ float agl(const float* p) {
  return __hip_atomic_load(p, __ATOMIC_RELAXED, __HIP_MEMORY_SCOPE_AGENT);
}
__device__ __forceinline__ void ags(float* p, float v) {
  __hip_atomic_store(p, v, __ATOMIC_RELAXED, __HIP_MEMORY_SCOPE_AGENT);
}

// Hand-rolled grid barrier: 2-level monotonic counter tree, relaxed agent atomics
// only — NO acquire/release fence, so no L2 invalidate / writeback ever executes.
__device__ __forceinline__ void gsync(uint32* bar, unsigned bep) {
  __syncthreads();
  if (threadIdx.x == 0) {
    asm volatile("s_waitcnt vmcnt(0)" ::: "memory");
    uint32* leaf = bar + (blockIdx.x >> 5) * 32;   // 8 leaves x 32 blocks, line-spaced
    uint32* root = bar + 256;
    uint32 prev = __hip_atomic_fetch_add(leaf, 1u, __ATOMIC_RELAXED, __HIP_MEMORY_SCOPE_AGENT);
    if (prev + 1u == 32u * bep)
      __hip_atomic_fetch_add(root, 1u, __ATOMIC_RELAXED, __HIP_MEMORY_SCOPE_AGENT);
    int spins = 0;
    while (__hip_atomic_load(root, __ATOMIC_RELAXED, __HIP_MEMORY_SCOPE_AGENT) < 8u * bep) {
      __builtin_amdgcn_s_sleep(2);
      if (++spins > 20000000) break;   // safety valve: fail instead of hang
    }
  }
  __syncthreads();
}

// sum over each 16-lane row via DPP (VALU pipe, no LDS)
__device__ __forceinline__ float rowsum16(float v) {
  int vi;
  vi = __float_as_int(v);
  v += __int_as_float(__builtin_amdgcn_update_dpp(0, vi, 0xB1, 0xF, 0xF, true));  // quad xor1
  vi = __float_as_int(v);
  v += __int_as_float(__builtin_amdgcn_update_dpp(0, vi, 0x4E, 0xF, 0xF, true));  // quad xor2
  vi = __float_as_int(v);
  v += __int_as_float(__builtin_amdgcn_update_dpp(0, vi, 0x124, 0xF, 0xF, true)); // row_ror:4
  vi = __float_as_int(v);
  v += __int_as_float(__builtin_amdgcn_update_dpp(0, vi, 0x128, 0xF, 0xF, true)); // row_ror:8
  return v;
}

// ---------------- prologue: LSTM weight packing (fp16, LDS-resident layouts) ----
__global__ __launch_bounds__(256) void k_pack_lstm2(
    const float* __restrict__ awih, const float* __restrict__ awhh,
    const float* __restrict__ dwih, const float* __restrict__ dwhh,
    uint32* __restrict__ wal, uint32* __restrict__ wdl, uint32* __restrict__ wdt)
{
  long gid = blockIdx.x * 256L + threadIdx.x;
  const long N1 = 3686400L, N2 = 4603904L, N3 = 655360L;
  if (gid < N1) {
    int blk = (int)(gid / 28800), rem = (int)(gid % 28800);
    int r2 = rem % 900;
    int ks = rem / 900;
    uint32 out = 0;
    if (r2 < 896) {
      int kq = r2 >> 4, rd = r2 & 15;
      int k = kq * 32 + ks;
      int rp0 = blk * 32 + 2 * rd, rp1 = rp0 + 1;
      int row0 = (rp0 & 3) * 1024 + (rp0 >> 2);
      int row1 = (rp1 & 3) * 1024 + (rp1 >> 2);
      float w0 = (k < 768) ? awih[(size_t)row0 * 768 + k] : awhh[(size_t)row0 * 1024 + k - 768];
      float w1 = (k < 768) ? awih[(size_t)row1 * 768 + k] : awhh[(size_t)row1 * 1024 + k - 768];
      __half2 h = __floats2half2_rn(w0, w1);
      out = *(uint32*)&h;
    }
    wal[gid] = out;
  } else if (gid < N1 + N2) {
    long g = gid - N1;
    int blk = (int)(g / 35968), rem = (int)(g % 35968);
    int r2 = rem % 1124;
    int ks = rem / 1124;
    uint32 out = 0;
    if (r2 < 1120) {
      int kq = r2 >> 4, rd = r2 & 15;
      int k = kq * 32 + ks;
      int rp0 = blk * 32 + 2 * rd, rp1 = rp0 + 1;
      int row0 = (rp0 & 3) * 1024 + (rp0 >> 2);
      int row1 = (rp1 & 3) * 1024 + (rp1 >> 2);
      float w0 = (k < 1536) ? dwih[(size_t)row0 * 1536 + k] : dwhh[(size_t)row0 * 1024 + k - 1536];
      float w1 = (k < 1536) ? dwih[(size_t)row1 * 1536 + k] : dwhh[(size_t)row1 * 1024 + k - 1536];
      __half2 h = __floats2half2_rn(w0, w1);
      out = *(uint32*)&h;
    }
    wdl[g] = out;
  } else if (gid < N1 + N2 + N3) {
    long g = gid - N1 - N2;
    int blk = (int)(g / 5120), rem = (int)(g % 5120);
    int rd2 = rem & 3, rg = (rem >> 2) & 3, ks = (rem >> 4) & 31, i = rem >> 9;
    int k = 2240 + 32 * i + ks;
    int r0 = rg * 8 + 2 * rd2;
    int rp0 = blk * 32 + r0, rp1 = rp0 + 1;
    int row0 = (rp0 & 3) * 1024 + (rp0 >> 2);
    int row1 = (rp1 & 3) * 1024 + (rp1 >> 2);
    float w0 = (k < 1536) ? dwih[(size_t)row0 * 1536 + k] : dwhh[(size_t)row0 * 1024 + k - 1536];
    float w1 = (k < 1536) ? dwih[(size_t)row1 * 1536 + k] : dwhh[(size_t)row1 * 1024 + k - 1536];
    __half2 h = __floats2half2_rn(w0, w1);
    wdt[g] = *(uint32*)&h;
  }
}

__global__ __launch_bounds__(256) void k_pack_small(
    const float* __restrict__ w1, const float* __restrict__ w2,
    const float* __restrict__ mw, const float* __restrict__ pw,
    const float* __restrict__ abih, const float* __restrict__ abhh,
    const float* __restrict__ dbih, const float* __restrict__ dbhh,
    const float* __restrict__ lw, const float* __restrict__ cw,
    float* __restrict__ w1t, float* __restrict__ w2t, float* __restrict__ mt,
    float* __restrict__ pjt, float* __restrict__ ba, float* __restrict__ bd,
    float* __restrict__ lc)
{
  int gid = blockIdx.x * 256 + threadIdx.x;
  if (gid < 20480) { int k = gid / 256, j = gid % 256; w1t[gid] = w1[j * 80 + k]; return; }
  gid -= 20480;
  if (gid < 65536) { int k = gid / 256, j = gid % 256; w2t[gid] = w2[j * 256 + k]; return; }
  gid -= 65536;
  if (gid < 65536) { int e = gid / 128, d = gid % 128; mt[gid] = mw[d * 512 + e]; return; }
  gid -= 65536;
  if (gid < 122880) { int k = gid / 80, m = gid % 80; pjt[gid] = pw[m * 1536 + k]; return; }
  gid -= 122880;
  if (gid < 4096) { int j = gid >> 2, g = gid & 3, row = g * 1024 + j; ba[gid] = abih[row] + abhh[row]; return; }
  gid -= 4096;
  if (gid < 4096) { int j = gid >> 2, g = gid & 3, row = g * 1024 + j; bd[gid] = dbih[row] + dbhh[row]; return; }
  gid -= 4096;
  if (gid < 7936) {
    int c = gid / (31 * 128), rem = gid % (31 * 128);
    int kk = rem / 128, d = rem % 128;
    float s = 0.f;
    for (int f = 0; f < 32; ++f) s += lw[d * 32 + f] * cw[(f * 2 + c) * 31 + kk];
    lc[gid] = s;
  }
}

// ---------------- prologue: prenet (verified) ----------------
__global__ __launch_bounds__(256) void k_prenet(
    const float* __restrict__ targets, const float* __restrict__ w1t,
    const float* __restrict__ b1, const float* __restrict__ w2t,
    const float* __restrict__ b2, float* __restrict__ pn)
{
  int t = blockIdx.x, tid = threadIdx.x;
  __shared__ float X[32][80];
  __shared__ float h1[256][33];
  for (int i = tid; i < 2560; i += 256) {
    int b = i / 80, m = i % 80;
    X[b][m] = (t == 0) ? 0.f : targets[((size_t)b * TD_ + (t - 1)) * NM_ + m];
  }
  __syncthreads();
  int j = tid;
  float bj = b1[j];
  for (int bt = 0; bt < 4; ++bt) {
    float acc[8];
#pragma unroll
    for (int i = 0; i < 8; ++i) acc[i] = bj;
    for (int k = 0; k < 80; ++k) {
      float w = w1t[k * 256 + j];
#pragma unroll
      for (int i = 0; i < 8; ++i) acc[i] += w * X[bt * 8 + i][k];
    }
#pragma unroll
    for (int i = 0; i < 8; ++i) h1[j][bt * 8 + i] = fmaxf(acc[i], 0.f);
  }
  __syncthreads();
  float cj = b2[j];
  float* out = pn + (size_t)t * PRE_ * B_;
  for (int bt = 0; bt < 4; ++bt) {
    float acc[8];
#pragma unroll
    for (int i = 0; i < 8; ++i) acc[i] = cj;
    for (int k = 0; k < 256; ++k) {
      float w = w2t[k * 256 + j];
#pragma unroll
      for (int i = 0; i < 8; ++i) acc[i] += w * h1[k][bt * 8 + i];
    }
#pragma unroll
    for (int i = 0; i < 8; ++i) out[j * 32 + bt * 8 + i] = fmaxf(acc[i], 0.f);
  }
}

// ---------------- prologue: processed_enc (verified) ----------------
__global__ __launch_bounds__(256) void k_penc(
    const float* __restrict__ enc, const float* __restrict__ mt,
    float* __restrict__ penc)
{
  int t = blockIdx.x, tid = threadIdx.x;
  __shared__ float encL[32][256];
  __shared__ float red[128][8][2];
  int d = tid & 127, s = tid >> 7;
  float acc[4][8];
#pragma unroll
  for (int bt = 0; bt < 4; ++bt)
#pragma unroll
    for (int i = 0; i < 8; ++i) acc[bt][i] = 0.f;
  for (int eh = 0; eh < 2; ++eh) {
    for (int i = tid; i < 8192; i += 256) {
      int b = i >> 8, e = i & 255;
      encL[b][e] = enc[((size_t)b * TE_ + t) * EH_ + eh * 256 + e];
    }
    __syncthreads();
    for (int bt = 0; bt < 4; ++bt) {
      for (int el = s * 128; el < s * 128 + 128; ++el) {
        float w = mt[(eh * 256 + el) * 128 + d];
#pragma unroll
        for (int i = 0; i < 8; ++i) acc[bt][i] += w * encL[bt * 8 + i][el];
      }
    }
    __syncthreads();
  }
  for (int bt = 0; bt < 4; ++bt) {
#pragma unroll
    for (int i = 0; i < 8; ++i) red[d][i][s] = acc[bt][i];
    __syncthreads();
    if (s == 0) {
#pragma unroll
      for (int i = 0; i < 8; ++i)
        penc[((size_t)t * AD_ + d) * 32 + bt * 8 + i] = red[d][i][0] + red[d][i][1];
    }
    __syncthreads();
  }
}

// ---------------- prologue: enc transpose to fp16 [b][e][t] ----------------
__global__ __launch_bounds__(256) void k_enct(
    const float* __restrict__ enc, __half* __restrict__ enct)
{
  int blk = blockIdx.x, tid = threadIdx.x;
  int b = blk >> 6, t0 = ((blk >> 3) & 7) * 64, e0 = (blk & 7) * 64;
  __shared__ float tile[64][65];
  for (int i = 0; i < 16; ++i) {
    int tl = i * 4 + (tid >> 6), e = tid & 63;
    tile[tl][e] = enc[((size_t)b * TE_ + t0 + tl) * EH_ + e0 + e];
  }
  __syncthreads();
  for (int i = 0; i < 16; ++i) {
    int el = i * 4 + (tid >> 6), tl = tid & 63;
    enct[((size_t)b * EH_ + e0 + el) * TE_ + t0 + tl] = __float2half(tile[tl][el]);
  }
}

// ---------------- persistent step kernel ----------------
struct KP {
  const uint32* wal; const uint32* wdl; const uint4* wdt;
  const float* pn; const float* penc; const __half* enct;
  const float* qw; const float* ww; const float* pjt; const float* pjb;
  const float* lc; const float* ba; const float* bd;
  float* ahv; float* ac; float* dhv; float* dc; float* ctxv; float* aw; float* aws;
  float* enp; float* mel; float* align;
  uint32* bar; int pv;
};

template<int T1, int T2>
__device__ __forceinline__ void stage_xc(int c, int nch,
    const float* __restrict__ xp0, const float* __restrict__ xp1,
    const float* __restrict__ xp2, float* __restrict__ XC,
    float4& st, int kidx, int b4)
{
  __syncthreads();
  *(float4*)&XC[kidx * 36 + b4] = st;
  __syncthreads();
  if (c + 1 < nch) {
    int kg = (c + 1) * 64 + kidx;
    const float* src = (kg < T1) ? xp0 + (size_t)kg * 32
                     : (kg < T2) ? xp1 + (size_t)(kg - T1) * 32
                                 : xp2 + (size_t)(kg - T2) * 32;
    st = *(const float4*)(src + b4);   // plain cached load (write-once versioned src)
  }
}

__device__ __forceinline__ void fma2(uint4 wv, const float* __restrict__ XC,
                                     int xb, float* acc)
{
  const __half2* hp = (const __half2*)&wv;
  float w[8];
#pragma unroll
  for (int d = 0; d < 4; ++d) {
    float2 f = __half22float2(hp[d]);
    w[2 * d] = f.x; w[2 * d + 1] = f.y;
  }
  float4 xa = *(const float4*)&XC[xb];
  float4 xc2 = *(const float4*)&XC[xb + 4];
  float x[8] = {xa.x, xa.y, xa.z, xa.w, xc2.x, xc2.y, xc2.z, xc2.w};
#pragma unroll
  for (int ri = 0; ri < 8; ++ri)
#pragma unroll
    for (int bi = 0; bi < 8; ++bi)
      acc[ri * 8 + bi] = fmaf(w[ri], x[bi], acc[ri * 8 + bi]);
}

__device__ __forceinline__ void lstm_finish(
    float* acc, float* __restrict__ GT, const float* __restrict__ bias,
    float* __restrict__ cst, float* __restrict__ hout,
    int rp0, int tid, int ks, int bq, int rg)
{
#pragma unroll
  for (int i = 0; i < 64; ++i) {
    float v = rowsum16(acc[i]);
    acc[i] = v + __shfl_xor(v, 16);
  }
  if (ks == 0) {
#pragma unroll
    for (int ri = 0; ri < 8; ++ri) {
      *(float4*)&GT[(rg * 8 + ri) * 32 + bq * 8] =
          make_float4(acc[ri * 8 + 0], acc[ri * 8 + 1], acc[ri * 8 + 2], acc[ri * 8 + 3]);
      *(float4*)&GT[(rg * 8 + ri) * 32 + bq * 8 + 4] =
          make_float4(acc[ri * 8 + 4], acc[ri * 8 + 5], acc[ri * 8 + 6], acc[ri * 8 + 7]);
    }
  }
  __syncthreads();
  if (tid < 256) {
    int jl = tid >> 5, b = tid & 31;
    float gi = GT[(jl * 4 + 0) * 32 + b] + bias[rp0 + jl * 4 + 0];
    float gf = GT[(jl * 4 + 1) * 32 + b] + bias[rp0 + jl * 4 + 1];
    float gg = GT[(jl * 4 + 2) * 32 + b] + bias[rp0 + jl * 4 + 2];
    float go = GT[(jl * 4 + 3) * 32 + b] + bias[rp0 + jl * 4 + 3];
    int j = (rp0 >> 2) + jl;
    float c0 = cst[j * 32 + b];                 // block-private: plain cached r/w
    float c2 = sigf(gf) * c0 + sigf(gi) * tanhf(gg);
    float h2 = sigf(go) * tanhf(c2);
    cst[j * 32 + b] = c2;
    ags(&hout[j * 32 + b], h2);                 // communicated: write-through to L3
  }
}

__device__ __forceinline__ void run_lstm_a(const KP& p, int t,
    const float* __restrict__ ah_in, const float* __restrict__ ctx_in,
    float* __restrict__ ah_out,
    uint32* WlU, float* XC, float* GT, int tid, int ks, int bq, int rg,
    int kidx, int b4, int blk)
{
  float acc[64];
#pragma unroll
  for (int i = 0; i < 64; ++i) acc[i] = 0.f;
  const float* xp0 = p.pn + (size_t)t * 8192;
  const float* xp1 = ctx_in;
  const float* xp2 = ah_in;
  float4 st;
  {
    int kg = kidx;
    const float* src = (kg < 256) ? xp0 + (size_t)kg * 32
                     : (kg < 768) ? xp1 + (size_t)(kg - 256) * 32
                                  : xp2 + (size_t)(kg - 768) * 32;
    st = *(const float4*)(src + b4);
  }
  const int wb = ks * 900 + rg * 4;
  const int xr = ks * 36 + bq * 8;
  for (int c = 0; c < 28; ++c) {
    stage_xc<256, 768>(c, 28, xp0, xp1, xp2, XC, st, kidx, b4);
    fma2(*(const uint4*)&WlU[wb + (2 * c) * 16], XC, xr, acc);
    fma2(*(const uint4*)&WlU[wb + (2 * c + 1) * 16], XC, xr + 32 * 36, acc);
  }
  lstm_finish(acc, GT, p.ba, p.ac, ah_out, blk * 32, tid, ks, bq, rg);
}

__device__ __forceinline__ void run_lstm_d(const KP& p,
    const float* __restrict__ xp0, const float* __restrict__ xp1,
    const float* __restrict__ xp2, float* __restrict__ dh_w,
    uint32* WlU, float* XC, float* GT, const uint4* wt,
    int tid, int ks, int bq, int rg, int kidx, int b4, int blk)
{
  float acc[64];
#pragma unroll
  for (int i = 0; i < 64; ++i) acc[i] = 0.f;
  float4 st;
  st = *(const float4*)(xp0 + (size_t)kidx * 32 + b4);  // chunk 0 all in xp0 (1024 wide)
  const int wb = ks * 1124 + rg * 4;
  const int xr = ks * 36 + bq * 8;
  for (int c = 0; c < 35; ++c) {
    stage_xc<1024, 1536>(c, 40, xp0, xp1, xp2, XC, st, kidx, b4);
    fma2(*(const uint4*)&WlU[wb + (2 * c) * 16], XC, xr, acc);
    fma2(*(const uint4*)&WlU[wb + (2 * c + 1) * 16], XC, xr + 32 * 36, acc);
  }
#pragma unroll
  for (int c2 = 0; c2 < 5; ++c2) {
    stage_xc<1024, 1536>(35 + c2, 40, xp0, xp1, xp2, XC, st, kidx, b4);
    fma2(wt[c2 * 2], XC, xr, acc);
    fma2(wt[c2 * 2 + 1], XC, xr + 32 * 36, acc);
  }
  lstm_finish(acc, GT, p.bd, p.dc, dh_w, (blk - 128) * 32, tid, ks, bq, rg);
}

__device__ __forceinline__ void mel_block(
    const float* __restrict__ dhp, const float* __restrict__ ctp,
    const float* __restrict__ pjt, const float* __restrict__ pjb,
    float* __restrict__ mel, int bb, int tt, float* S, int tid)
{
  float* xo = S + 1536;
  float* ro = S + 3072;
  for (int i = tid; i < 1536; i += 512)
    xo[i] = (i < 1024) ? dhp[i * 32 + bb] : ctp[(i - 1024) * 32 + bb];
  __syncthreads();
  if (tid < 480) {
    int m = tid % 80, k2 = tid / 80;
    float a2 = 0.f;
    for (int k = k2 * 256; k < k2 * 256 + 256; ++k) a2 += pjt[k * 80 + m] * xo[k];
    ro[m * 8 + k2] = a2;
  }
  __syncthreads();
  if (tid < 80) {
    float s3 = pjb[tid];
#pragma unroll
    for (int k = 0; k < 6; ++k) s3 += ro[tid * 8 + k];
    mel[((size_t)bb * TD_ + tt) * NM_ + tid] = s3;
  }
}

__global__ __launch_bounds__(512) void k_step(KP p)
{
  extern __shared__ float LDSF[];
  const int blk = blockIdx.x, tid = threadIdx.x;
  const int ks = tid & 31, bq = (tid >> 5) & 3, rg = tid >> 7;
  const int kidx = tid >> 3, b4 = (tid & 7) * 4;
  const bool isA = blk < 128;
  float* SC = LDSF + (isA ? 28800 : 35968);
  float* XC = SC;
  float* GT = SC + 2304;
  uint32* WlU = (uint32*)LDSF;
  unsigned bep = 0;

  // one-time: weights into LDS (+VGPR tail for D)
  {
    const uint32* src = isA ? p.wal + (size_t)blk * 28800
                            : p.wdl + (size_t)(blk - 128) * 35968;
    int n4 = isA ? 7200 : 8992;
    for (int i = tid; i < n4; i += 512)
      ((uint4*)WlU)[i] = ((const uint4*)src)[i];
  }
  uint4 wt[10];
  if (!isA) {
#pragma unroll
    for (int i = 0; i < 10; ++i)
      wt[i] = p.wdt[(size_t)(blk - 128) * 1280 + (i * 32 + ks) * 4 + rg];
  }
  __syncthreads();

  for (int t = 0; t < TD_; ++t) {
    // version slots: slot ver(s)=s%pv holds state INPUT to step s (written at s-1)
    const int vc = t % p.pv;
    const int vn = (t + 1) % p.pv;
    const int vp = (t > 0) ? (t - 1) % p.pv : 0;
    const float* ah_in  = p.ahv + (size_t)vc * 32768;
    float*       ah_out = p.ahv + (size_t)vn * 32768;
    const float* ctx_in = p.ctxv + (size_t)vc * 16384;
    float*       ctx_out= p.ctxv + (size_t)vn * 16384;

    // ---- PA: lstm_a(t) [0..127] || lstm_d(t-1) [128..255] ----
    if (isA) {
      run_lstm_a(p, t, ah_in, ctx_in, ah_out, WlU, XC, GT, tid, ks, bq, rg, kidx, b4, blk);
    } else if (t > 0) {
      run_lstm_d(p, ah_in, ctx_in,
                 p.dhv + (size_t)vp * 32768, p.dhv + (size_t)vc * 32768,
                 WlU, XC, GT, wt, tid, ks, bq, rg, kidx, b4, blk);
    }
    bep += 1; gsync(p.bar, bep);
    // ---- PB: q (from ah slot vn, LDS-chunked) + location conv + energies ----
    {
      int tc = blk >> 3, ds = blk & 7;
      int t0 = tc * 16, d0 = ds * 16;
      float* qs  = SC;            // 512
      float* wws = SC + 512;      // 16
      float* AHC = SC + 528;      // 2048 (chunk buffer, later reused by win/lcs)
      float* win = SC + 528;      // 2944
      float* lcs = SC + 528 + 2944; // 992
      if (tid < 16) wws[tid] = p.ww[d0 + tid];
      int bb2 = tid & 31, dl = tid >> 5;
      {
        const float* ahsrc = p.ahv + (size_t)vn * 32768;
        const float* qbase = p.qw + (size_t)(d0 + dl) * 1024;
        float qacc = 0.f;
        float4 pf = *(const float4*)(ahsrc + tid * 4);
        for (int ch = 0; ch < 16; ++ch) {
          __syncthreads();
          *(float4*)(AHC + tid * 4) = pf;
          __syncthreads();
          if (ch < 15) pf = *(const float4*)(ahsrc + (ch + 1) * 2048 + tid * 4);
          const float* qrow = qbase + ch * 64;
#pragma unroll
          for (int jj = 0; jj < 64; jj += 4) {
            float4 qv = *(const float4*)(qrow + jj);
            qacc = fmaf(qv.x, AHC[(jj + 0) * 32 + bb2], qacc);
            qacc = fmaf(qv.y, AHC[(jj + 1) * 32 + bb2], qacc);
            qacc = fmaf(qv.z, AHC[(jj + 2) * 32 + bb2], qacc);
            qacc = fmaf(qv.w, AHC[(jj + 3) * 32 + bb2], qacc);
          }
        }
        __syncthreads();
        qs[dl * 32 + bb2] = qacc;
      }
      for (int i = tid; i < 2944; i += 512) {
        int c = i / 1472, r = (i >> 5) % 46, bb = i & 31;
        int tg = t0 - 15 + r;
        float v = 0.f;
        if (tg >= 0 && tg < 512) v = agl((c ? p.aws : p.aw) + tg * 32 + bb);
        win[i] = v;
      }
      for (int i = tid; i < 992; i += 512) {
        int c = i / 496, kk = (i >> 4) % 31, dl2 = i & 15;
        lcs[i] = p.lc[(c * 31 + kk) * 128 + d0 + dl2];
      }
      __syncthreads();
      {
        int bb = tid & 31, th = tid >> 5;
        int tt = t0 + th;
        float pa[16];
#pragma unroll
        for (int i = 0; i < 16; ++i) pa[i] = 0.f;
        for (int c = 0; c < 2; ++c) {
          for (int kk = 0; kk < 31; ++kk) {
            float wv = win[c * 1472 + (th + kk) * 32 + bb];
            const float4* lr = (const float4*)(lcs + c * 496 + kk * 16);
            float4 l0 = lr[0], l1 = lr[1], l2 = lr[2], l3 = lr[3];
            pa[0]  += l0.x * wv; pa[1]  += l0.y * wv; pa[2]  += l0.z * wv; pa[3]  += l0.w * wv;
            pa[4]  += l1.x * wv; pa[5]  += l1.y * wv; pa[6]  += l1.z * wv; pa[7]  += l1.w * wv;
            pa[8]  += l2.x * wv; pa[9]  += l2.y * wv; pa[10] += l2.z * wv; pa[11] += l2.w * wv;
            pa[12] += l3.x * wv; pa[13] += l3.y * wv; pa[14] += l3.z * wv; pa[15] += l3.w * wv;
          }
        }
        float epv = 0.f;
#pragma unroll
        for (int dl2 = 0; dl2 < 16; ++dl2) {
          float v = qs[dl2 * 32 + bb] + p.penc[((size_t)tt * 128 + d0 + dl2) * 32 + bb] + pa[dl2];
          epv += wws[dl2] * tanhf(v);
        }
        ags(&p.enp[(size_t)bb * 4096 + tt * 8 + ds], epv);
      }
    }
    bep += 1; gsync(p.bar, bep);
    // ---- PC: softmax + ctx (+aw/aws/align, +mel(t-1)) ----
    {
      int bb = blk >> 3, et = blk & 7;
      float* Sr  = SC;
      float* awL = SC + 512;
      float* cr  = SC + 1024;
      const float* epb = p.enp + (size_t)bb * 4096 + tid * 8;
      float e = agl(epb) + agl(epb + 1) + agl(epb + 2) + agl(epb + 3)
              + agl(epb + 4) + agl(epb + 5) + agl(epb + 6) + agl(epb + 7);
      Sr[tid] = e; __syncthreads();
      for (int off = 256; off; off >>= 1) {
        if (tid < off) Sr[tid] = fmaxf(Sr[tid], Sr[tid + off]);
        __syncthreads();
      }
      float mx = Sr[0]; __syncthreads();
      float x = expf(e - mx);
      Sr[tid] = x; __syncthreads();
      for (int off = 256; off; off >>= 1) {
        if (tid < off) Sr[tid] += Sr[tid + off];
        __syncthreads();
      }
      float a = x * (1.f / Sr[0]);
      awL[tid] = a;
      __syncthreads();
      int el = tid & 63, ts = tid >> 6;
      const __half2* eb = (const __half2*)(p.enct +
          ((size_t)(bb * 512 + et * 64 + el)) * 512 + ts * 64);
      float acc = 0.f;
#pragma unroll 8
      for (int i = 0; i < 32; ++i) {
        float2 f = __half22float2(eb[i]);
        acc += awL[ts * 64 + 2 * i] * f.x + awL[ts * 64 + 2 * i + 1] * f.y;
      }
      cr[ts * 64 + el] = acc;
      __syncthreads();
      if (tid < 64) {
        float s2 = 0.f;
#pragma unroll
        for (int k = 0; k < 8; ++k) s2 += cr[k * 64 + tid];
        ags(&ctx_out[(et * 64 + tid) * 32 + bb], s2);
      }
      if (et == 0) {
        ags(&p.aw[tid * 32 + bb], a);
        float os = agl(&p.aws[tid * 32 + bb]);
        ags(&p.aws[tid * 32 + bb], os + a);
        p.align[((size_t)bb * TD_ + t) * TE_ + tid] = a;
      }
      if (et == 1 && t > 0) {
        mel_block(p.dhv + (size_t)vc * 32768, p.ctxv + (size_t)vc * 16384,
                  p.pjt, p.pjb, p.mel, bb, t - 1, SC, tid);
      }
    }
    bep += 1; gsync(p.bar, bep);
  }
  // ---- epilogue: lstm_d(511) then mel(511) ----
  {
    const int v511 = 511 % p.pv, v512 = 512 % p.pv;
    if (!isA) {
      run_lstm_d(p, p.ahv + (size_t)v512 * 32768, p.ctxv + (size_t)v512 * 16384,
                 p.dhv + (size_t)v511 * 32768, p.dhv + (size_t)v512 * 32768,
                 WlU, XC, GT, wt, tid, ks, bq, rg, kidx, b4, blk);
    }
    bep += 1; gsync(p.bar, bep);
    if (blk < 32) {
      mel_block(p.dhv + (size_t)v512 * 32768, p.ctxv + (size_t)v512 * 16384,
                p.pjt, p.pjb, p.mel, blk, 511, SC, tid);
    }
  }
}

extern "C" void kernel_launch(void* const* d_in, const int* in_sizes, int n_in,
                              void* d_out, int out_size, void* d_ws, size_t ws_size,
                              hipStream_t stream)
{
  const float* enc     = (const float*)d_in[0];
  const float* targets = (const float*)d_in[1];
  const float* pw1  = (const float*)d_in[2];
  const float* pb1  = (const float*)d_in[3];
  const float* pw2  = (const float*)d_in[4];
  const float* pb2  = (const float*)d_in[5];
  const float* mw   = (const float*)d_in[6];
  const float* qw   = (const float*)d_in[7];
  const float* www  = (const float*)d_in[8];
  const float* lw   = (const float*)d_in[9];
  const float* cw   = (const float*)d_in[10];
  const float* awih = (const float*)d_in[11];
  const float* awhh = (const float*)d_in[12];
  const float* abih = (const float*)d_in[13];
  const float* abhh = (const float*)d_in[14];
  const float* dwih = (const float*)d_in[15];
  const float* dwhh = (const float*)d_in[16];
  const float* dbih = (const float*)d_in[17];
  const float* dbhh = (const float*)d_in[18];
  const float* pjw  = (const float*)d_in[19];
  const float* pjb  = (const float*)d_in[20];

  uint32* wsb = (uint32*)d_ws;
  size_t o = 0;
  auto F = [&](size_t n) { size_t r = o; o += n; return r; };
  size_t oWAL = F(3686400), oWDL = F(4603904), oWDT = F(655360);
  size_t oENCT = F(4194304);           // 8,388,608 halfs
  size_t oPN = F(4194304), oPENC = F(2097152);
  size_t oW1T = F(20480), oW2T = F(65536), oMT = F(65536), oPJT = F(122880);
  size_t oLC = F(7936), oBA = F(4096), oBD = F(4096);
  size_t oZR = o;                      // zeroed region start
  size_t oAC = F(32768), oDC = F(32768), oAW = F(16384), oAWS = F(16384), oBAR = F(1024);
  size_t zr_dw = o - oZR;
  o = (o + 31) & ~(size_t)31;          // 128B-align versioned space (line isolation)
  size_t fixed_dw = o;
  size_t avail_dw = ws_size / 4;
  long pvl = (avail_dw > fixed_dw) ? (long)((avail_dw - fixed_dw) / 81920) : 0;
  int pv = (pvl < 3) ? 3 : (pvl > 513 ? 513 : (int)pvl);
  size_t oAHV = F((size_t)pv * 32768);
  size_t oDHV = F((size_t)pv * 32768);
  size_t oCTXV = F((size_t)pv * 16384);
  size_t oENP = oW1T;                  // alias: 131,072 <= 151,552 (W1T+W2T+MT)

  hipMemsetAsync(wsb + oZR, 0, zr_dw * 4, stream);
  hipMemsetAsync(wsb + oAHV, 0, (size_t)32768 * 4, stream);
  hipMemsetAsync(wsb + oDHV, 0, (size_t)32768 * 4, stream);
  hipMemsetAsync(wsb + oCTXV, 0, (size_t)16384 * 4, stream);

  float* mel = (float*)d_out;
  float* align = mel + (size_t)B_ * TD_ * NM_;

  k_pack_lstm2<<<34944, 256, 0, stream>>>(awih, awhh, dwih, dwhh,
                                          wsb + oWAL, wsb + oWDL, wsb + oWDT);
  k_pack_small<<<1135, 256, 0, stream>>>(pw1, pw2, mw, pjw, abih, abhh, dbih, dbhh,
                                         lw, cw,
                                         (float*)(wsb + oW1T), (float*)(wsb + oW2T),
                                         (float*)(wsb + oMT), (float*)(wsb + oPJT),
                                         (float*)(wsb + oBA), (float*)(wsb + oBD),
                                         (float*)(wsb + oLC));
  k_prenet<<<512, 256, 0, stream>>>(targets, (float*)(wsb + oW1T), pb1,
                                    (float*)(wsb + oW2T), pb2, (float*)(wsb + oPN));
  k_penc<<<512, 256, 0, stream>>>(enc, (float*)(wsb + oMT), (float*)(wsb + oPENC));
  k_enct<<<2048, 256, 0, stream>>>(enc, (__half*)(wsb + oENCT));

  KP kp;
  kp.wal = wsb + oWAL; kp.wdl = wsb + oWDL; kp.wdt = (const uint4*)(wsb + oWDT);
  kp.pn = (float*)(wsb + oPN); kp.penc = (float*)(wsb + oPENC);
  kp.enct = (__half*)(wsb + oENCT);
  kp.qw = qw; kp.ww = www; kp.pjt = (float*)(wsb + oPJT); kp.pjb = pjb;
  kp.lc = (float*)(wsb + oLC); kp.ba = (float*)(wsb + oBA); kp.bd = (float*)(wsb + oBD);
  kp.ahv = (float*)(wsb + oAHV); kp.ac = (float*)(wsb + oAC);
  kp.dhv = (float*)(wsb + oDHV); kp.dc = (float*)(wsb + oDC);
  kp.ctxv = (float*)(wsb + oCTXV);
  kp.aw = (float*)(wsb + oAW); kp.aws = (float*)(wsb + oAWS);
  kp.enp = (float*)(wsb + oENP); kp.mel = mel; kp.align = align;
  kp.bar = wsb + oBAR; kp.pv = pv;

  hipFuncSetAttribute((const void*)k_step,
                      hipFuncAttributeMaxDynamicSharedMemorySize, 161728);
  void* kargs[] = { &kp };
  hipLaunchCooperativeKernel((const void*)k_step, dim3(256), dim3(512), kargs,
                             161728, stream);
}